// Round 1
// baseline (1137.147 us; speedup 1.0000x reference)
//
#include <hip/hip_runtime.h>
#include <stdint.h>

#define PI_F      3.14159265358979323846f
#define TWO_PI_F  6.28318530717958647692f
#define DT_F      0.05f
#define DIFF_SCALE_F 0.3f

typedef short short8 __attribute__((ext_vector_type(8)));
typedef float f32x4 __attribute__((ext_vector_type(4)));
typedef int   i32x4 __attribute__((ext_vector_type(4)));
typedef unsigned int u32x4 __attribute__((ext_vector_type(4)));

__device__ __forceinline__ unsigned short f2bf(float x) {
    unsigned int u = __float_as_uint(x);
    u += 0x7FFFu + ((u >> 16) & 1u);
    return (unsigned short)(u >> 16);
}
__device__ __forceinline__ float bf2f(unsigned short h) {
    return __uint_as_float(((unsigned int)h) << 16);
}
__device__ __forceinline__ float sigf(float x) {
    return 1.0f / (1.0f + __expf(-x));
}
__device__ __forceinline__ float tanhfast(float x) {
    return 1.0f - 2.0f / (1.0f + __expf(2.0f * x));
}
__device__ __forceinline__ float siluf(float x) {
    return x / (1.0f + __expf(-x));
}
__device__ __forceinline__ float wrapf(float t) {
    float w = fmodf(t + PI_F, TWO_PI_F);
    w = (w < 0.0f) ? w + TWO_PI_F : w;
    return w - PI_F;
}
__device__ __forceinline__ float dot4(const float* __restrict__ W, const float* __restrict__ X, int K) {
    float a = 0.0f;
#pragma unroll 4
    for (int kk = 0; kk < K; kk += 4) {
        f32x4 wv = *(const f32x4*)(W + kk);
        f32x4 xv = *(const f32x4*)(X + kk);
        a += wv[0]*xv[0] + wv[1]*xv[1] + wv[2]*xv[2] + wv[3]*xv[3];
    }
    return a;
}

// ---------------- K0: convert GRU weights to bf16 ----------------
__global__ void prep_kernel(const float* __restrict__ wih, const float* __restrict__ whh,
                            unsigned short* __restrict__ wihb, unsigned short* __restrict__ whhb) {
    int i = blockIdx.x * 256 + threadIdx.x;
    if (i < 384*512) wihb[i] = f2bf(wih[i]);
    if (i < 384*128) whhb[i] = f2bf(whh[i]);
}

// ---------------- K1: gi = [sin|cos](context) @ wih^T  (bf16 MFMA) ----------------
// M = T*B = 262144 (m = t*1024 + b), N = 384, K = 512. BM=128, BN=384 (full), Kd-tile=64.
__launch_bounds__(512)
__global__ void gi_gemm_kernel(const float* __restrict__ ctx_ang,
                               const unsigned short* __restrict__ wihb,
                               unsigned short* __restrict__ gi) {
    __shared__ __align__(16) unsigned short As[2][128*64];  // [sin/cos][row][64 k], 16B-granule swizzled

    const int tid = threadIdx.x;
    const int lane = tid & 63;
    const int w  = tid >> 6;     // 0..7
    const int wm = w >> 2;       // 0..1 (M half)
    const int wn = w & 3;        // 0..3 (N quarter: 96 cols)
    const int l15 = lane & 15;
    const int l4  = lane >> 4;
    const int mt = blockIdx.x;   // 0..2047
    const int t  = mt >> 3;
    const int b0 = (mt & 7) * 128;

    const int srow = tid >> 2;   // 0..127 staging row
    const int q    = tid & 3;    // quarter of 64 d-values

    f32x4 acc[4][6];
    const f32x4 z4 = {0.0f, 0.0f, 0.0f, 0.0f};
#pragma unroll
    for (int mi = 0; mi < 4; ++mi)
#pragma unroll
        for (int ns = 0; ns < 6; ++ns) acc[mi][ns] = z4;

    for (int dt = 0; dt < 4; ++dt) {
        // --- load 16 context values, compute sin+cos, pack bf16 (in regs) ---
        float v[16];
        {
            const float* src = ctx_ang + ((size_t)(b0 + srow) * 256 + t) * 256 + dt*64 + q*16;
#pragma unroll
            for (int j = 0; j < 4; ++j) {
                f32x4 x = *(const f32x4*)(src + j*4);
#pragma unroll
                for (int i = 0; i < 4; ++i) v[j*4+i] = x[i];
            }
        }
        unsigned int us[8], uc[8];
#pragma unroll
        for (int p = 0; p < 8; ++p) {
            float a0 = v[2*p], a1 = v[2*p+1];
            us[p] = (unsigned int)f2bf(__sinf(a0)) | ((unsigned int)f2bf(__sinf(a1)) << 16);
            uc[p] = (unsigned int)f2bf(__cosf(a0)) | ((unsigned int)f2bf(__cosf(a1)) << 16);
        }
        __syncthreads();   // previous iteration's fragment reads complete
#pragma unroll
        for (int gg = 0; gg < 2; ++gg) {
            int g  = q*2 + gg;
            int gs = g ^ (srow & 7);
            u32x4 ws = { us[gg*4+0], us[gg*4+1], us[gg*4+2], us[gg*4+3] };
            u32x4 wc = { uc[gg*4+0], uc[gg*4+1], uc[gg*4+2], uc[gg*4+3] };
            *(u32x4*)((char*)&As[0][0] + srow*128 + gs*16) = ws;
            *(u32x4*)((char*)&As[1][0] + srow*128 + gs*16) = wc;
        }
        __syncthreads();

        // --- MFMA over both halves (sin -> k base dt*64, cos -> 256 + dt*64) ---
#pragma unroll
        for (int half = 0; half < 2; ++half) {
            const char* Ab = (const char*)&As[half][0];
            const int kbase = half*256 + dt*64;
#pragma unroll
            for (int ki = 0; ki < 2; ++ki) {
                short8 aF[4], bF[6];
#pragma unroll
                for (int mi = 0; mi < 4; ++mi) {
                    int row = wm*64 + mi*16 + l15;
                    int kg  = ki*4 + l4;
                    aF[mi] = *(const short8*)(Ab + row*128 + ((kg ^ (row & 7)))*16);
                }
#pragma unroll
                for (int ns = 0; ns < 6; ++ns) {
                    int col = wn*96 + ns*16 + l15;
                    bF[ns] = *(const short8*)(wihb + (size_t)col*512 + kbase + ki*32 + l4*8);
                }
#pragma unroll
                for (int mi = 0; mi < 4; ++mi)
#pragma unroll
                    for (int ns = 0; ns < 6; ++ns)
                        acc[mi][ns] = __builtin_amdgcn_mfma_f32_16x16x32_bf16(aF[mi], bF[ns], acc[mi][ns], 0, 0, 0);
            }
        }
    }

    // --- epilogue: write gi bf16, layout gi[(t*1024+b)*384 + j] ---
    const size_t mbase = (size_t)mt * 128;
#pragma unroll
    for (int mi = 0; mi < 4; ++mi) {
#pragma unroll
        for (int ns = 0; ns < 6; ++ns) {
            int col = wn*96 + ns*16 + l15;
            size_t mrow = mbase + wm*64 + mi*16 + l4*4;
#pragma unroll
            for (int r = 0; r < 4; ++r)
                gi[(mrow + r)*384 + col] = f2bf(acc[mi][ns][r]);
        }
    }
}

// ---------------- K2: GRU scan + proj + SDE (4 batch rows per block) ----------------
__launch_bounds__(256)
__global__ void scan_sde_kernel(const float* __restrict__ ctx_ang,
                                const float* __restrict__ dW,
                                const unsigned short* __restrict__ whhb,
                                const float* __restrict__ gru_b,
                                const float* __restrict__ gru_bn,
                                const float* __restrict__ proj_w,
                                const float* __restrict__ proj_b,
                                const float* __restrict__ dr_w0, const float* __restrict__ dr_b0,
                                const float* __restrict__ dr_w1, const float* __restrict__ dr_b1,
                                const float* __restrict__ dr_w2, const float* __restrict__ dr_b2,
                                const float* __restrict__ dr_w3, const float* __restrict__ dr_b3,
                                const float* __restrict__ df_w0, const float* __restrict__ df_b0,
                                const float* __restrict__ df_w1, const float* __restrict__ df_b1,
                                const float* __restrict__ df_w2, const float* __restrict__ df_b2,
                                const unsigned short* __restrict__ gi,
                                float* __restrict__ out) {
    __shared__ __align__(16) unsigned short hA[16*128];      // bf16 A-tile (rows 0..3 valid), swizzled
    __shared__ __align__(16) float h32[4*128];               // fp32 hidden state
    __shared__ __align__(16) float gh[384*4];                // gh[j][b]
    __shared__ __align__(16) unsigned short giB[2][4*384];   // gi double buffer
    __shared__ __align__(16) float bias[512];                // gru_b(384) | gru_bn(128)
    __shared__ __align__(16) float th[4*256];
    __shared__ __align__(16) float ctxs[4*64];
    __shared__ __align__(16) float inp[4*576];
    __shared__ __align__(16) float hb1[4*128];
    __shared__ __align__(16) float hb2[4*128];
    __shared__ __align__(16) float mus[4*256];

    const int tid  = threadIdx.x;
    const int lane = tid & 63;
    const int w    = tid >> 6;        // wave 0..3
    const int l15  = lane & 15;
    const int l4   = lane >> 4;
    const int b0   = blockIdx.x * 4;  // batch rows b0..b0+3
    const int c0   = w * 32;          // this wave's 32 h-columns

    // --- init LDS ---
    {
        u32x4 z = {0u,0u,0u,0u};
        *(u32x4*)((char*)hA + tid*16) = z;        // 256*16 = 4096 B
    }
#pragma unroll
    for (int e = 0; e < 2; ++e) h32[tid + e*256] = 0.0f;
    {
        int i1 = tid;       bias[i1] = (i1 < 384) ? gru_b[i1] : gru_bn[i1 - 384];
        int i2 = tid + 256; bias[i2] = (i2 < 384) ? gru_b[i2] : gru_bn[i2 - 384];
    }
    if (tid < 192)
        *(i32x4*)&giB[0][tid*8] = *(const i32x4*)(gi + (size_t)b0*384 + tid*8);

    // --- whh fragments in registers: wave w handles cols {c0..c0+32} of each gate ---
    short8 whB[6][4];
#pragma unroll
    for (int g2 = 0; g2 < 6; ++g2) {
        int g = g2 >> 1, hf = g2 & 1;
        int j = g*128 + c0 + hf*16 + l15;
#pragma unroll
        for (int kt = 0; kt < 4; ++kt)
            whB[g2][kt] = *(const short8*)(whhb + (size_t)j*128 + kt*32 + l4*8);
    }
    __syncthreads();

    // ==== GRU scan over T=256 ====
    for (int t = 0; t < 256; ++t) {
        i32x4 pf;
        const bool dopf = (t < 255) && (tid < 192);
        if (dopf) pf = *(const i32x4*)(gi + ((size_t)(t+1)*1024 + b0)*384 + tid*8);

        short8 aF[4];
#pragma unroll
        for (int kt = 0; kt < 4; ++kt) {
            int kg = kt*4 + l4;
            aF[kt] = *(const short8*)((const char*)hA + l15*256 + ((kg ^ (l15 & 7)) & 15)*16);
        }
        f32x4 acc[6];
        const f32x4 z4 = {0.0f,0.0f,0.0f,0.0f};
#pragma unroll
        for (int g2 = 0; g2 < 6; ++g2) acc[g2] = z4;
#pragma unroll
        for (int kt = 0; kt < 4; ++kt)
#pragma unroll
            for (int g2 = 0; g2 < 6; ++g2)
                acc[g2] = __builtin_amdgcn_mfma_f32_16x16x32_bf16(aF[kt], whB[g2][kt], acc[g2], 0, 0, 0);

        if (lane < 16) {   // rows 0..3 live in lanes 0..15 as float4
#pragma unroll
            for (int g2 = 0; g2 < 6; ++g2) {
                int g = g2 >> 1, hf = g2 & 1;
                int j = g*128 + c0 + hf*16 + l15;
                *(f32x4*)&gh[j*4] = acc[g2];
            }
        }
        __syncthreads();

        // gate math: all 256 threads, 2 (b,j) units each
        const unsigned short* gcur = &giB[t & 1][0];
#pragma unroll
        for (int e = 0; e < 2; ++e) {
            int idx = tid*2 + e;
            int b = idx >> 7, j = idx & 127;
            float ir  = bf2f(gcur[b*384 + j])       + bias[j];
            float iz  = bf2f(gcur[b*384 + 128 + j]) + bias[128 + j];
            float in_ = bf2f(gcur[b*384 + 256 + j]) + bias[256 + j];
            float hr = gh[j*4 + b];
            float hz = gh[(128 + j)*4 + b];
            float hn = gh[(256 + j)*4 + b];
            float r = sigf(ir + hr);
            float z = sigf(iz + hz);
            float n = tanhfast(in_ + r*(hn + bias[384 + j]));
            float hold = h32[b*128 + j];
            float hnew = n + z*(hold - n);
            h32[b*128 + j] = hnew;
            int gnum = j >> 3;
            *(unsigned short*)((char*)hA + b*256 + ((gnum ^ b))*16 + (j & 7)*2) = f2bf(hnew);
        }
        if (dopf) *(i32x4*)&giB[(t+1) & 1][tid*8] = pf;
        __syncthreads();
    }

    // ==== ctx = h_final @ proj_w^T + proj_b ====
    {
        int b = tid >> 6, c = tid & 63;
        ctxs[b*64 + c] = proj_b[c] + dot4(proj_w + (size_t)c*128, h32 + b*128, 128);
    }
    // ==== theta init ====
#pragma unroll
    for (int e = 0; e < 4; ++e) {
        int idx = tid + e*256;
        int b = idx >> 8, i = idx & 255;
        th[idx] = wrapf(ctx_ang[((size_t)(b0 + b)*256 + 255)*256 + i]);
    }
    __syncthreads();

    // ==== SDE: 5 Euler steps ====
    for (int k = 0; k < 5; ++k) {
        for (int e = 0; e < 9; ++e) {            // inp = [sin th | cos th | ctx]
            int idx = tid + e*256;               // 0..2303
            int b = idx / 576;
            int i = idx - b*576;
            float vv;
            if (i < 256)       vv = __sinf(th[(b<<8) + i]);
            else if (i < 512)  vv = __cosf(th[(b<<8) + i - 256]);
            else               vv = ctxs[(b<<6) + i - 512];
            inp[idx] = vv;
        }
        __syncthreads();
#pragma unroll
        for (int e = 0; e < 2; ++e) {            // drift L0: 576 -> 128
            int o = tid*2 + e; int b = o >> 7, j = o & 127;
            hb1[o] = siluf(dr_b0[j] + dot4(dr_w0 + (size_t)j*576, inp + b*576, 576));
        }
        __syncthreads();
#pragma unroll
        for (int e = 0; e < 2; ++e) {            // drift L1
            int o = tid*2 + e; int b = o >> 7, j = o & 127;
            hb2[o] = siluf(dr_b1[j] + dot4(dr_w1 + (size_t)j*128, hb1 + b*128, 128));
        }
        __syncthreads();
#pragma unroll
        for (int e = 0; e < 2; ++e) {            // drift L2
            int o = tid*2 + e; int b = o >> 7, j = o & 127;
            hb1[o] = siluf(dr_b2[j] + dot4(dr_w2 + (size_t)j*128, hb2 + b*128, 128));
        }
        __syncthreads();
#pragma unroll
        for (int e = 0; e < 4; ++e) {            // drift L3: 128 -> 256 (mu)
            int o = tid + e*256; int b = o >> 8, j = o & 255;
            mus[o] = dr_b3[j] + dot4(dr_w3 + (size_t)j*128, hb1 + b*128, 128);
        }
        __syncthreads();
#pragma unroll
        for (int e = 0; e < 2; ++e) {            // diff L0: 576 -> 128
            int o = tid*2 + e; int b = o >> 7, j = o & 127;
            hb2[o] = siluf(df_b0[j] + dot4(df_w0 + (size_t)j*576, inp + b*576, 576));
        }
        __syncthreads();
#pragma unroll
        for (int e = 0; e < 2; ++e) {            // diff L1
            int o = tid*2 + e; int b = o >> 7, j = o & 127;
            hb1[o] = siluf(df_b1[j] + dot4(df_w1 + (size_t)j*128, hb2 + b*128, 128));
        }
        __syncthreads();
#pragma unroll
        for (int e = 0; e < 4; ++e) {            // diff L2 + softplus + theta update
            int o = tid + e*256; int b = o >> 8, j = o & 255;
            float a = df_b2[j] + dot4(df_w2 + (size_t)j*128, hb1 + b*128, 128);
            float sp = (a > 15.0f) ? a : log1pf(__expf(a));
            float sg = sp * DIFF_SCALE_F;
            float dw = dW[((size_t)(b0 + b)*5 + k)*256 + j];
            th[(b<<8) + j] = wrapf(th[(b<<8) + j] + mus[o]*DT_F + sg*dw);
        }
        __syncthreads();
    }

    // ==== write theta ====
#pragma unroll
    for (int e = 0; e < 4; ++e) {
        int idx = tid + e*256;
        out[(size_t)b0*256 + idx] = th[idx];
    }
}

extern "C" void kernel_launch(void* const* d_in, const int* in_sizes, int n_in,
                              void* d_out, int out_size, void* d_ws, size_t ws_size,
                              hipStream_t stream) {
    const float* ctx_ang = (const float*)d_in[0];
    const float* dW      = (const float*)d_in[1];
    const float* wih     = (const float*)d_in[2];
    const float* whh     = (const float*)d_in[3];
    const float* gru_b   = (const float*)d_in[4];
    const float* gru_bn  = (const float*)d_in[5];
    const float* proj_w  = (const float*)d_in[6];
    const float* proj_b  = (const float*)d_in[7];
    const float* dr_w0   = (const float*)d_in[8];
    const float* dr_b0   = (const float*)d_in[9];
    const float* dr_w1   = (const float*)d_in[10];
    const float* dr_b1   = (const float*)d_in[11];
    const float* dr_w2   = (const float*)d_in[12];
    const float* dr_b2   = (const float*)d_in[13];
    const float* dr_w3   = (const float*)d_in[14];
    const float* dr_b3   = (const float*)d_in[15];
    const float* df_w0   = (const float*)d_in[16];
    const float* df_b0   = (const float*)d_in[17];
    const float* df_w1   = (const float*)d_in[18];
    const float* df_b1   = (const float*)d_in[19];
    const float* df_w2   = (const float*)d_in[20];
    const float* df_b2   = (const float*)d_in[21];
    float* out = (float*)d_out;

    unsigned short* gi   = (unsigned short*)d_ws;              // 262144*384 bf16 = 201.3 MB
    unsigned short* wihb = gi + (size_t)262144*384;            // 384*512 bf16
    unsigned short* whhb = wihb + (size_t)384*512;             // 384*128 bf16

    prep_kernel<<<768, 256, 0, stream>>>(wih, whh, wihb, whhb);
    gi_gemm_kernel<<<2048, 512, 0, stream>>>(ctx_ang, wihb, gi);
    scan_sde_kernel<<<256, 256, 0, stream>>>(ctx_ang, dW, whhb, gru_b, gru_bn,
        proj_w, proj_b, dr_w0, dr_b0, dr_w1, dr_b1, dr_w2, dr_b2, dr_w3, dr_b3,
        df_w0, df_b0, df_w1, df_b1, df_w2, df_b2, gi, out);
}